// Round 3
// baseline (46766.998 us; speedup 1.0000x reference)
//
#include <hip/hip_runtime.h>

// ESN forward scan on MI355X — R3.
//
// h_t = tanh(W_in x_t + W_res h_{t-1}), 7168 strictly-sequential steps.
// One persistent kernel, 256 WGs x 512 threads (8 waves), all co-resident.
//
// R2 post-mortem: VGPR_Count=124 < the 128 needed for W alone => the compiler
// REMATERIALIZED the W_res loads inside the loop (legal: const __restrict__
// source). Each step re-streamed 64 MB of W from L3 (L1/L2 killed by the
// per-step acquire fence) ~= 2.5-4 us/step, matching the 6.5 us step time and
// the low FETCH_SIZE (L3 absorbed it). R3 fix: pass every loaded W element
// through an empty `asm volatile("" : "+v")` barrier — values become opaque,
// rematerialization is impossible, W must stay resident (VGPR/AGPR).

#define RES    4096
#define TST    7168
#define TSEQ   28
#define NWG    256
#define TPB    512     // 8 waves
#define WAVES  8
#define RPW    2       // rows per wave; 8*256*2 = 4096 rows

// d_ws: [0,1024) flags (256 u32, zeroed each launch); [1024, +32KB) h dbl buffer
#define WS_NEEDED (1024 + 2 * RES * 4)

// Make a float opaque to the optimizer: kills load-rematerialization.
#define OPAQUE(v) asm volatile("" : "+v"(v))
#define OPAQUE4(f4) do { OPAQUE((f4).x); OPAQUE((f4).y); OPAQUE((f4).z); OPAQUE((f4).w); } while (0)

__global__ __launch_bounds__(TPB, 2)
void esn_scan(const float* __restrict__ x,
              const float* __restrict__ Win,
              const float* __restrict__ Wres,
              const float* __restrict__ Wout,
              const float* __restrict__ h0,
              float* __restrict__ out,
              unsigned* __restrict__ flags,
              float* __restrict__ hbuf)
{
    const int tid  = threadIdx.x;
    const int wv   = tid >> 6;         // wave 0..7
    const int lane = tid & 63;
    const int wg   = blockIdx.x;
    const int rb   = wg * 16 + wv * RPW;   // this wave's first row

    __shared__ float hlds[RES];            // staged h_{t-1} (16 KB)
    __shared__ float outred[WAVES][16];    // readout partials (cols 0..9 used)

    // ---- one-time: this wave's 2 W_res rows into registers (32 x float4) ----
    float4 W0[16], W1[16];
    {
        const float* r0 = Wres + (size_t)(rb + 0) * RES;
        const float* r1 = Wres + (size_t)(rb + 1) * RES;
#pragma unroll
        for (int c = 0; c < 16; ++c) {
            W0[c] = *reinterpret_cast<const float4*>(r0 + c * 256 + lane * 4);
            W1[c] = *reinterpret_cast<const float4*>(r1 + c * 256 + lane * 4);
        }
#pragma unroll
        for (int c = 0; c < 16; ++c) { OPAQUE4(W0[c]); OPAQUE4(W1[c]); }
    }
    // W_in slices (lane i<28 holds Win[row][i]) and W_out slices (lane o<10)
    float Wi0 = (lane < TSEQ) ? Win[(rb + 0) * TSEQ + lane] : 0.f;
    float Wi1 = (lane < TSEQ) ? Win[(rb + 1) * TSEQ + lane] : 0.f;
    OPAQUE(Wi0); OPAQUE(Wi1);
    const float Wo0 = (lane < 10) ? Wout[lane * RES + rb + 0] : 0.f;
    const float Wo1 = (lane < 10) ? Wout[lane * RES + rb + 1] : 0.f;

    float xv = (lane < TSEQ) ? x[lane] : 0.f;   // x row for t=0
    int budget = 1500000;                        // anti-hang: terminate, never spin forever
    int tmod = 0, b = 0;

    for (int t = 0; t < TST; ++t) {
        // ---- gate: wave 0 alone waits until every WG published h_{t-1} ----
        if (t > 0) {
            if (wv == 0) {
                const unsigned tgt = (unsigned)t;
                const unsigned* fp = flags + lane * 4;
                for (;;) {
                    unsigned f0 = __hip_atomic_load(fp + 0, __ATOMIC_RELAXED, __HIP_MEMORY_SCOPE_AGENT);
                    unsigned f1 = __hip_atomic_load(fp + 1, __ATOMIC_RELAXED, __HIP_MEMORY_SCOPE_AGENT);
                    unsigned f2 = __hip_atomic_load(fp + 2, __ATOMIC_RELAXED, __HIP_MEMORY_SCOPE_AGENT);
                    unsigned f3 = __hip_atomic_load(fp + 3, __ATOMIC_RELAXED, __HIP_MEMORY_SCOPE_AGENT);
                    if (__all(min(min(f0, f1), min(f2, f3)) >= tgt)) break;
                    if (--budget < 0) break;
                }
                __builtin_amdgcn_fence(__ATOMIC_ACQUIRE, "agent");  // inv L1/L2 before h loads
            }
            __syncthreads();                                        // B1: h_{t-1} visible
        }

        // ---- stage h_{t-1} into LDS: 2 fully-coalesced float4 per thread ----
        {
            const float* hsrc = (t == 0) ? h0 : (hbuf + (size_t)RES * ((t & 1) ^ 1));
            float4 a = *reinterpret_cast<const float4*>(hsrc + tid * 4);
            float4 c = *reinterpret_cast<const float4*>(hsrc + 2048 + tid * 4);
            *reinterpret_cast<float4*>(hlds + tid * 4)        = a;
            *reinterpret_cast<float4*>(hlds + 2048 + tid * 4) = c;
        }
        __syncthreads();                                            // B2: LDS h ready

        // prefetch next step's x (independent of recurrence; hides under FMAs)
        float xnext = 0.f;
        if (t + 1 < TST && lane < TSEQ) xnext = x[(t + 1) * TSEQ + lane];

        // ---- per-row dot products: h consumed from LDS one float4 at a time ----
        float4 a0 = {0.f, 0.f, 0.f, 0.f}, a1 = {0.f, 0.f, 0.f, 0.f};
#pragma unroll
        for (int c = 0; c < 16; ++c) {
            float4 h4 = *reinterpret_cast<const float4*>(hlds + c * 256 + lane * 4);
            a0.x += W0[c].x * h4.x; a0.y += W0[c].y * h4.y;
            a0.z += W0[c].z * h4.z; a0.w += W0[c].w * h4.w;
            a1.x += W1[c].x * h4.x; a1.y += W1[c].y * h4.y;
            a1.z += W1[c].z * h4.z; a1.w += W1[c].w * h4.w;
        }
        float s0 = (a0.x + a0.y) + (a0.z + a0.w) + Wi0 * xv;
        float s1 = (a1.x + a1.y) + (a1.z + a1.w) + Wi1 * xv;
        xv = xnext;

        // ---- 64-lane butterfly (broadcasts totals to all lanes) ----
#pragma unroll
        for (int m = 32; m; m >>= 1) {
            s0 += __shfl_xor(s0, m, 64);
            s1 += __shfl_xor(s1, m, 64);
        }

        // tanh(s) = 1 - 2/(e^{2s}+1); overflow-safe
        float e0 = __expf(2.f * s0), e1 = __expf(2.f * s1);
        float h0v = 1.f - __fdividef(2.f, e0 + 1.f);
        float h1v = 1.f - __fdividef(2.f, e1 + 1.f);

        // ---- publish this wave's 2 h values (write-through to coherence point) ----
        if (lane < RPW) {
            float sv = lane ? h1v : h0v;
            __hip_atomic_store(hbuf + (size_t)RES * (t & 1) + rb + lane, sv,
                               __ATOMIC_RELAXED, __HIP_MEMORY_SCOPE_AGENT);
        }

        const bool last = (tmod == TSEQ - 1);
        if (last && lane < 10)
            outred[wv][lane] = Wo0 * h0v + Wo1 * h1v;

        __syncthreads();   // B3: drains each wave's vmcnt -> h stores visible before flag

        if (tid == 0)
            __hip_atomic_store(flags + wg, (unsigned)(t + 1),
                               __ATOMIC_RELEASE, __HIP_MEMORY_SCOPE_AGENT);

        // ---- fused readout at each batch element's final step ----
        if (last) {
            if (tid < 10) {
                float s = outred[0][tid] + outred[1][tid] + outred[2][tid] + outred[3][tid]
                        + outred[4][tid] + outred[5][tid] + outred[6][tid] + outred[7][tid];
                unsafeAtomicAdd(out + b * 10 + tid, s);
            }
            tmod = 0; ++b;
        } else {
            ++tmod;
        }
    }
}

extern "C" void kernel_launch(void* const* d_in, const int* in_sizes, int n_in,
                              void* d_out, int out_size, void* d_ws, size_t ws_size,
                              hipStream_t stream)
{
    (void)in_sizes; (void)n_in;
    if (ws_size < WS_NEEDED) return;

    const float* x    = (const float*)d_in[0];
    const float* Win  = (const float*)d_in[1];
    const float* Wres = (const float*)d_in[2];
    const float* Wout = (const float*)d_in[3];
    const float* h0   = (const float*)d_in[4];
    float*       out  = (float*)d_out;

    unsigned* flags = (unsigned*)d_ws;
    float*    hbuf  = (float*)((char*)d_ws + 1024);

    // ws/out are re-poisoned 0xAA before every timed call:
    hipMemsetAsync(d_ws, 0, 1024, stream);                              // flags -> 0
    hipMemsetAsync(d_out, 0, (size_t)out_size * sizeof(float), stream); // atomics accumulate

    esn_scan<<<NWG, TPB, 0, stream>>>(x, Win, Wres, Wout, h0, out, flags, hbuf);
}

// Round 6
// 35516.022 us; speedup vs baseline: 1.3168x; 1.3168x over previous
//
#include <hip/hip_runtime.h>

// ESN forward scan on MI355X — R4 design (3rd submit; R4/R5 slots lost to
// GPU-acquisition timeouts). Fence-free h-exchange protocol.
//
// R3 post-mortem: R2 and R3 ran in IDENTICAL time (6.5us/step) despite
// completely different W-residency codegen => the kernel is SYNC-PROTOCOL
// bound, not W-bound. The per-step agent acquire fence (buffer_inv: L1+L2
// invalidate) and release fence (L2 writeback) x 256 WGs x 7168 steps are
// the cost. This design removes ALL fences:
//  - h is exchanged ONLY via agent-scope relaxed atomics (bypass the
//    non-coherent L1/L2, hit the coherence point). Bypass loads can't read
//    stale lines -> no acquire fence needed.
//  - producer order: h atomic stores -> vmcnt(0) drain + barrier -> relaxed
//    flag store. In-order issue makes h visible before the flag -> no
//    release fence needed.
//  - Consequence: L1/L2 stay warm across all 7168 steps (W, x, Wout, spill).
// Shape: 256 WGs x 1024 threads (16 waves), 1 row/wave -> W = 16 float4 =
// 64 VGPR/thread (need ~100, cap 128 @ 4 waves/SIMD) — allocator out of the
// danger zone that spilled R1-R3's 128-reg W.

#define RES    4096
#define TST    7168
#define TSEQ   28
#define NWG    256
#define TPB    1024    // 16 waves
#define WAVES  16

// d_ws: [0,1024) flags (256 u32, zeroed each launch); [1024, +32KB) h dbl buffer
#define WS_NEEDED (1024 + 2 * RES * 4)

// Make a value opaque: kills load-rematerialization inside the loop.
#define OPAQUE(v) asm volatile("" : "+v"(v))
#define OPAQUE4(f4) do { OPAQUE((f4).x); OPAQUE((f4).y); OPAQUE((f4).z); OPAQUE((f4).w); } while (0)

__global__ __launch_bounds__(TPB, 4)
void esn_scan(const float* __restrict__ x,
              const float* __restrict__ Win,
              const float* __restrict__ Wres,
              const float* __restrict__ Wout,
              const float* __restrict__ h0,
              float* __restrict__ out,
              unsigned* __restrict__ flags,
              float* __restrict__ hbuf)
{
    const int tid  = threadIdx.x;
    const int wv   = tid >> 6;          // wave 0..15
    const int lane = tid & 63;
    const int wg   = blockIdx.x;
    const int row  = wg * 16 + wv;      // this wave's reservoir row

    __shared__ float hlds[RES];          // staged h_{t-1} (16 KB)
    __shared__ float outred[WAVES][16];  // readout partials (cols 0..9 used)

    // ---- one-time: this wave's W_res row into registers (16 x float4) ----
    float4 W[16];
    {
        const float* wr = Wres + (size_t)row * RES;
#pragma unroll
        for (int c = 0; c < 16; ++c)
            W[c] = *reinterpret_cast<const float4*>(wr + c * 256 + lane * 4);
#pragma unroll
        for (int c = 0; c < 16; ++c) OPAQUE4(W[c]);
    }
    float Wi = (lane < TSEQ) ? Win[row * TSEQ + lane] : 0.f;   // input-proj slice
    OPAQUE(Wi);
    const float Wo = (lane < 10) ? Wout[lane * RES + row] : 0.f; // readout slice

    float xv = (lane < TSEQ) ? x[lane] : 0.f;   // x row for t=0
    int budget = 1500000;                        // anti-hang: terminate, never spin
    int tmod = 0, b = 0;

    for (int t = 0; t < TST; ++t) {
        // ---- gate: wave 0 polls 256 flags (bypass loads, coherence point) ----
        if (t > 0 && wv == 0) {
            const unsigned tgt = (unsigned)t;
            const unsigned* fp = flags + lane * 4;
            for (;;) {
                unsigned f0 = __hip_atomic_load(fp + 0, __ATOMIC_RELAXED, __HIP_MEMORY_SCOPE_AGENT);
                unsigned f1 = __hip_atomic_load(fp + 1, __ATOMIC_RELAXED, __HIP_MEMORY_SCOPE_AGENT);
                unsigned f2 = __hip_atomic_load(fp + 2, __ATOMIC_RELAXED, __HIP_MEMORY_SCOPE_AGENT);
                unsigned f3 = __hip_atomic_load(fp + 3, __ATOMIC_RELAXED, __HIP_MEMORY_SCOPE_AGENT);
                if (__all(min(min(f0, f1), min(f2, f3)) >= tgt)) break;
                if (--budget < 0) break;
            }
            // NO acquire fence: subsequent h loads bypass L1/L2 themselves.
        }
        __syncthreads();   // B1: releases all 16 waves once flags observed

        // ---- stage h_{t-1} into LDS via bypass loads (4 floats/thread) ----
        {
            const float* hsrc = (t == 0) ? h0 : (hbuf + (size_t)RES * ((t & 1) ^ 1));
            const float* p = hsrc + tid * 4;
            float4 hv4;
            hv4.x = __hip_atomic_load(p + 0, __ATOMIC_RELAXED, __HIP_MEMORY_SCOPE_AGENT);
            hv4.y = __hip_atomic_load(p + 1, __ATOMIC_RELAXED, __HIP_MEMORY_SCOPE_AGENT);
            hv4.z = __hip_atomic_load(p + 2, __ATOMIC_RELAXED, __HIP_MEMORY_SCOPE_AGENT);
            hv4.w = __hip_atomic_load(p + 3, __ATOMIC_RELAXED, __HIP_MEMORY_SCOPE_AGENT);
            *reinterpret_cast<float4*>(hlds + tid * 4) = hv4;  // ds_write_b128, conflict-free
        }
        __syncthreads();   // B2: LDS h ready

        // prefetch next step's x (plain cached load — caches stay warm now)
        float xnext = 0.f;
        if (t + 1 < TST && lane < TSEQ) xnext = x[(t + 1) * TSEQ + lane];

        // ---- row dot product: 16 ds_read_b128 + 64 FMA per lane ----
        float4 a4 = {0.f, 0.f, 0.f, 0.f};
#pragma unroll
        for (int c = 0; c < 16; ++c) {
            float4 h4 = *reinterpret_cast<const float4*>(hlds + c * 256 + lane * 4);
            a4.x += W[c].x * h4.x; a4.y += W[c].y * h4.y;
            a4.z += W[c].z * h4.z; a4.w += W[c].w * h4.w;
        }
        float s = (a4.x + a4.y) + (a4.z + a4.w) + Wi * xv;  // fold input proj
        xv = xnext;

        // 64-lane butterfly (broadcasts total to all lanes)
#pragma unroll
        for (int m = 32; m; m >>= 1) s += __shfl_xor(s, m, 64);

        // tanh(s) = 1 - 2/(e^{2s}+1); overflow-safe (exp->inf => 1)
        float e0 = __expf(2.f * s);
        float hv = 1.f - __fdividef(2.f, e0 + 1.f);

        // ---- publish h[row] (bypass store to coherence point) ----
        if (lane == 0)
            __hip_atomic_store(hbuf + (size_t)RES * (t & 1) + row, hv,
                               __ATOMIC_RELAXED, __HIP_MEMORY_SCOPE_AGENT);

        const bool last = (tmod == TSEQ - 1);
        if (last && lane < 10) outred[wv][lane] = Wo * hv;

        asm volatile("s_waitcnt vmcnt(0)" ::: "memory");  // insurance: h stores drained
        __syncthreads();   // B3: all waves' stores complete before flag

        if (tid == 0)
            __hip_atomic_store(flags + wg, (unsigned)(t + 1),
                               __ATOMIC_RELAXED, __HIP_MEMORY_SCOPE_AGENT);

        // ---- fused readout at each batch element's final step ----
        if (last) {
            if (tid < 10) {
                float sum = 0.f;
#pragma unroll
                for (int w = 0; w < WAVES; ++w) sum += outred[w][tid];
                unsafeAtomicAdd(out + b * 10 + tid, sum);
            }
            tmod = 0; ++b;
        } else {
            ++tmod;
        }
    }
}

extern "C" void kernel_launch(void* const* d_in, const int* in_sizes, int n_in,
                              void* d_out, int out_size, void* d_ws, size_t ws_size,
                              hipStream_t stream)
{
    (void)in_sizes; (void)n_in;
    if (ws_size < WS_NEEDED) return;

    const float* x    = (const float*)d_in[0];
    const float* Win  = (const float*)d_in[1];
    const float* Wres = (const float*)d_in[2];
    const float* Wout = (const float*)d_in[3];
    const float* h0   = (const float*)d_in[4];
    float*       out  = (float*)d_out;

    unsigned* flags = (unsigned*)d_ws;
    float*    hbuf  = (float*)((char*)d_ws + 1024);

    // ws/out are re-poisoned 0xAA before every timed call:
    hipMemsetAsync(d_ws, 0, 1024, stream);                              // flags -> 0
    hipMemsetAsync(d_out, 0, (size_t)out_size * sizeof(float), stream); // atomics accumulate

    esn_scan<<<NWG, TPB, 0, stream>>>(x, Win, Wres, Wout, h0, out, flags, hbuf);
}

// Round 9
// 34556.174 us; speedup vs baseline: 1.3534x; 1.0278x over previous
//
#include <hip/hip_runtime.h>

// ESN forward scan on MI355X — R7 design (3rd submit; two prior slots lost to
// GPU-acquisition timeouts). W_res parked in AGPRs via explicit asm.
//
// History: R1-R3 sync-fence-bound (6.5us/step). R6 (fence-free protocol)
// = 4.58us/step, VGPR_Count=52 => W STILL spilled to scratch (transient
// init pressure > 128-reg cap made the allocator evict the long W ranges),
// re-streaming ~64MB/step from L3 (~2.5-3.5us/step, matches residual).
//
// R7 fix: W lives in 64 AGPRs per lane, moved there with explicit
// v_accvgpr_write_b32 at init and fetched with volatile v_accvgpr_read_b32
// INSIDE the step loop. The in-loop volatile asm demands the value be in an
// AGPR every iteration -> the allocator cannot spill W. AGPRs are otherwise
// unused; 64 AGPR + ~55 arch VGPR fits the 128 combined/wave budget at
// 4 waves/SIMD. Init stages one float4 at a time (AGPR writes release the
// staging regs) -> no transient pressure spike.
//
// Everything else identical to R6 (fence-free agent-atomic h exchange,
// wave0-poll + 3 barriers, LDS h staging, fused readout).

#define RES    4096
#define TST    7168
#define TSEQ   28
#define NWG    256
#define TPB    1024    // 16 waves
#define WAVES  16

// d_ws: [0,1024) flags (256 u32, zeroed each launch); [1024, +32KB) h dbl buffer
#define WS_NEEDED (1024 + 2 * RES * 4)

#define OPAQUE(v) asm volatile("" : "+v"(v))
// AGPR park/fetch (gfx950: unified file, AGPRs addressable via 'a' constraint)
#define AWR(dst, src) asm volatile("v_accvgpr_write_b32 %0, %1" : "=a"(dst) : "v"(src))
#define ARD(dst, src) asm volatile("v_accvgpr_read_b32 %0, %1"  : "=v"(dst) : "a"(src))

__global__ __launch_bounds__(TPB, 4)
void esn_scan(const float* __restrict__ x,
              const float* __restrict__ Win,
              const float* __restrict__ Wres,
              const float* __restrict__ Wout,
              const float* __restrict__ h0,
              float* __restrict__ out,
              unsigned* __restrict__ flags,
              float* __restrict__ hbuf)
{
    const int tid  = threadIdx.x;
    const int wv   = tid >> 6;          // wave 0..15
    const int lane = tid & 63;
    const int wg   = blockIdx.x;
    const int row  = wg * 16 + wv;      // this wave's reservoir row

    __shared__ float hlds[RES];          // staged h_{t-1} (16 KB)
    __shared__ float outred[WAVES][16];  // readout partials (cols 0..9 used)

    // ---- one-time: this wave's W_res row -> 64 AGPRs per lane ----
    // Load one float4 at a time; AWR frees the staging regs immediately, so
    // peak arch-VGPR pressure at init stays tiny (no spill trigger).
    float Wa[64];   // every access below is compile-time indexed (fully unrolled)
    {
        const float* wr = Wres + (size_t)row * RES;
#pragma unroll
        for (int c = 0; c < 16; ++c) {
            float4 tv = *reinterpret_cast<const float4*>(wr + c * 256 + lane * 4);
            AWR(Wa[4 * c + 0], tv.x);
            AWR(Wa[4 * c + 1], tv.y);
            AWR(Wa[4 * c + 2], tv.z);
            AWR(Wa[4 * c + 3], tv.w);
        }
    }
    float Wi = (lane < TSEQ) ? Win[row * TSEQ + lane] : 0.f;   // input-proj slice
    OPAQUE(Wi);
    const float Wo = (lane < 10) ? Wout[lane * RES + row] : 0.f; // readout slice

    float xv = (lane < TSEQ) ? x[lane] : 0.f;   // x row for t=0
    int budget = 1500000;                        // anti-hang: terminate, never spin
    int tmod = 0, b = 0;

    for (int t = 0; t < TST; ++t) {
        // ---- gate: wave 0 polls 256 flags (bypass loads, coherence point) ----
        if (t > 0 && wv == 0) {
            const unsigned tgt = (unsigned)t;
            const unsigned* fp = flags + lane * 4;
            for (;;) {
                unsigned f0 = __hip_atomic_load(fp + 0, __ATOMIC_RELAXED, __HIP_MEMORY_SCOPE_AGENT);
                unsigned f1 = __hip_atomic_load(fp + 1, __ATOMIC_RELAXED, __HIP_MEMORY_SCOPE_AGENT);
                unsigned f2 = __hip_atomic_load(fp + 2, __ATOMIC_RELAXED, __HIP_MEMORY_SCOPE_AGENT);
                unsigned f3 = __hip_atomic_load(fp + 3, __ATOMIC_RELAXED, __HIP_MEMORY_SCOPE_AGENT);
                if (__all(min(min(f0, f1), min(f2, f3)) >= tgt)) break;
                if (--budget < 0) break;
            }
            // No acquire fence: h loads below bypass L1/L2 themselves.
        }
        __syncthreads();   // B1: releases all 16 waves once flags observed

        // ---- stage h_{t-1} into LDS via bypass loads (4 floats/thread) ----
        {
            const float* hsrc = (t == 0) ? h0 : (hbuf + (size_t)RES * ((t & 1) ^ 1));
            const float* p = hsrc + tid * 4;
            float4 hv4;
            hv4.x = __hip_atomic_load(p + 0, __ATOMIC_RELAXED, __HIP_MEMORY_SCOPE_AGENT);
            hv4.y = __hip_atomic_load(p + 1, __ATOMIC_RELAXED, __HIP_MEMORY_SCOPE_AGENT);
            hv4.z = __hip_atomic_load(p + 2, __ATOMIC_RELAXED, __HIP_MEMORY_SCOPE_AGENT);
            hv4.w = __hip_atomic_load(p + 3, __ATOMIC_RELAXED, __HIP_MEMORY_SCOPE_AGENT);
            *reinterpret_cast<float4*>(hlds + tid * 4) = hv4;  // ds_write_b128, conflict-free
        }
        __syncthreads();   // B2: LDS h ready

        // prefetch next step's x (plain cached load — caches stay warm)
        float xnext = 0.f;
        if (t + 1 < TST && lane < TSEQ) xnext = x[(t + 1) * TSEQ + lane];

        // ---- row dot product: per c, 4 accvgpr_read + ds_read_b128 + 4 FMA ----
        float4 a4 = {0.f, 0.f, 0.f, 0.f};
#pragma unroll
        for (int c = 0; c < 16; ++c) {
            float4 h4 = *reinterpret_cast<const float4*>(hlds + c * 256 + lane * 4);
            float w0, w1, w2, w3;
            ARD(w0, Wa[4 * c + 0]);
            ARD(w1, Wa[4 * c + 1]);
            ARD(w2, Wa[4 * c + 2]);
            ARD(w3, Wa[4 * c + 3]);
            a4.x += w0 * h4.x; a4.y += w1 * h4.y;
            a4.z += w2 * h4.z; a4.w += w3 * h4.w;
        }
        float s = (a4.x + a4.y) + (a4.z + a4.w) + Wi * xv;  // fold input proj
        xv = xnext;

        // 64-lane butterfly (broadcasts total to all lanes)
#pragma unroll
        for (int m = 32; m; m >>= 1) s += __shfl_xor(s, m, 64);

        // tanh(s) = 1 - 2/(e^{2s}+1); overflow-safe (exp->inf => 1)
        float e0 = __expf(2.f * s);
        float hv = 1.f - __fdividef(2.f, e0 + 1.f);

        // ---- publish h[row] (bypass store to coherence point) ----
        if (lane == 0)
            __hip_atomic_store(hbuf + (size_t)RES * (t & 1) + row, hv,
                               __ATOMIC_RELAXED, __HIP_MEMORY_SCOPE_AGENT);

        const bool last = (tmod == TSEQ - 1);
        if (last && lane < 10) outred[wv][lane] = Wo * hv;

        asm volatile("s_waitcnt vmcnt(0)" ::: "memory");  // h stores drained
        __syncthreads();   // B3: all waves' stores complete before flag

        if (tid == 0)
            __hip_atomic_store(flags + wg, (unsigned)(t + 1),
                               __ATOMIC_RELAXED, __HIP_MEMORY_SCOPE_AGENT);

        // ---- fused readout at each batch element's final step ----
        if (last) {
            if (tid < 10) {
                float sum = 0.f;
#pragma unroll
                for (int w = 0; w < WAVES; ++w) sum += outred[w][tid];
                unsafeAtomicAdd(out + b * 10 + tid, sum);
            }
            tmod = 0; ++b;
        } else {
            ++tmod;
        }
    }
}

extern "C" void kernel_launch(void* const* d_in, const int* in_sizes, int n_in,
                              void* d_out, int out_size, void* d_ws, size_t ws_size,
                              hipStream_t stream)
{
    (void)in_sizes; (void)n_in;
    if (ws_size < WS_NEEDED) return;

    const float* x    = (const float*)d_in[0];
    const float* Win  = (const float*)d_in[1];
    const float* Wres = (const float*)d_in[2];
    const float* Wout = (const float*)d_in[3];
    const float* h0   = (const float*)d_in[4];
    float*       out  = (float*)d_out;

    // ws/out are re-poisoned 0xAA before every timed call:
    unsigned* flags = (unsigned*)d_ws;
    float*    hbuf  = (float*)((char*)d_ws + 1024);

    hipMemsetAsync(d_ws, 0, 1024, stream);                              // flags -> 0
    hipMemsetAsync(d_out, 0, (size_t)out_size * sizeof(float), stream); // atomics accumulate

    esn_scan<<<NWG, TPB, 0, stream>>>(x, Win, Wres, Wout, h0, out, flags, hbuf);
}